// Round 1
// baseline (575.281 us; speedup 1.0000x reference)
//
#include <hip/hip_runtime.h>
#include <hip/hip_bf16.h>
#include <cstdint>
#include <cstddef>

#define B_ 4
#define S_ 2048
#define T_ 2048
#define C_ 256

// ---------------------------------------------------------------------------
// Canonicalize masks (bool-byte / int32 / float32 storage all handled).
// Element index 1 is True in this problem (all lens >= 1024), so:
//   byte layout  -> byte[1] == 1
//   4-byte layout-> byte[1] == 0  (int 1 = 01 00 00 00, float 1.0 = 00 00 80 3F)
// ---------------------------------------------------------------------------
__global__ void build_masks_kernel(const void* __restrict__ src_mask,
                                   const void* __restrict__ tgt_mask,
                                   int* __restrict__ smask, int* __restrict__ tmask) {
    int i = blockIdx.x * blockDim.x + threadIdx.x;
    const unsigned char* sb = (const unsigned char*)src_mask;
    const unsigned char* tb = (const unsigned char*)tgt_mask;
    bool s_is_byte = (sb[1] != 0);
    bool t_is_byte = (tb[1] != 0);
    if (i < B_ * S_)
        smask[i] = s_is_byte ? (sb[i] != 0) : (((const int*)src_mask)[i] != 0);
    if (i < B_ * T_)
        tmask[i] = t_is_byte ? (tb[i] != 0) : (((const int*)tgt_mask)[i] != 0);
}

// ---------------------------------------------------------------------------
// Generic f32 NT GEMM: Out[m,n] = scale * sum_k A[m,k]*B[n,k]
// A: [M,K] row-major (lda=K), B: [N,K] row-major (ldb=K), Out: [M,N] (ldo=N)
// 64x64 block tile, K-chunks of 64 staged transposed in LDS, 4x4 per thread.
// ---------------------------------------------------------------------------
__global__ __launch_bounds__(256) void gemm_nt_kernel(
    const float* __restrict__ A, const float* __restrict__ Bm, float* __restrict__ Out,
    int M, int N, int K, long sA, long sB, long sO, float scale)
{
    __shared__ float As[64][68];   // [k][m], +4 pad keeps 16B alignment, low conflicts
    __shared__ float Bs[64][68];   // [k][n]
    const int tid = threadIdx.x;
    const int z = blockIdx.z;
    A  += (size_t)z * sA;
    Bm += (size_t)z * sB;
    Out+= (size_t)z * sO;
    const int n0 = blockIdx.x * 64, m0 = blockIdx.y * 64;
    const int c4 = tid & 15;   // float4 column in k-chunk
    const int rl = tid >> 4;   // 16 rows per pass
    const int tx = tid & 15, ty = tid >> 4;
    float acc[4][4] = {};

    for (int k0 = 0; k0 < K; k0 += 64) {
        #pragma unroll
        for (int p = 0; p < 4; ++p) {
            int row = p * 16 + rl;
            float4 a = *(const float4*)(A  + (size_t)(m0 + row) * K + k0 + c4 * 4);
            As[c4*4+0][row] = a.x; As[c4*4+1][row] = a.y;
            As[c4*4+2][row] = a.z; As[c4*4+3][row] = a.w;
            float4 b = *(const float4*)(Bm + (size_t)(n0 + row) * K + k0 + c4 * 4);
            Bs[c4*4+0][row] = b.x; Bs[c4*4+1][row] = b.y;
            Bs[c4*4+2][row] = b.z; Bs[c4*4+3][row] = b.w;
        }
        __syncthreads();
        #pragma unroll 8
        for (int k = 0; k < 64; ++k) {
            float4 av = *(const float4*)&As[k][ty * 4];
            float4 bv = *(const float4*)&Bs[k][tx * 4];
            float aa[4] = {av.x, av.y, av.z, av.w};
            float bb[4] = {bv.x, bv.y, bv.z, bv.w};
            #pragma unroll
            for (int i = 0; i < 4; ++i)
                #pragma unroll
                for (int j = 0; j < 4; ++j)
                    acc[i][j] = fmaf(aa[i], bb[j], acc[i][j]);
        }
        __syncthreads();
    }
    #pragma unroll
    for (int i = 0; i < 4; ++i) {
        float4 o = make_float4(acc[i][0]*scale, acc[i][1]*scale,
                               acc[i][2]*scale, acc[i][3]*scale);
        *(float4*)(Out + (size_t)(m0 + ty*4 + i) * N + n0 + tx * 4) = o;
    }
}

// ---------------------------------------------------------------------------
// Row softmax stats over t (axis=2), masked by tgt_mask: rowstats[row] = (max, sumexp)
// One 256-thread block per row (b*S+s); row kept in registers.
// ---------------------------------------------------------------------------
__global__ __launch_bounds__(256) void rowstats_kernel(
    const float* __restrict__ sim, const int* __restrict__ tmask,
    float* __restrict__ rowstats)
{
    const int row = blockIdx.x;       // b*S + s
    const int b = row >> 11;
    const float* p = sim + (size_t)row * T_;
    const int* tm = tmask + b * T_;
    float v[8];
    #pragma unroll
    for (int k = 0; k < 8; ++k) {
        int t = threadIdx.x + k * 256;
        float x = p[t];
        v[k] = tm[t] ? x : -INFINITY;
    }
    float m = -INFINITY;
    #pragma unroll
    for (int k = 0; k < 8; ++k) m = fmaxf(m, v[k]);
    #pragma unroll
    for (int off = 32; off; off >>= 1) m = fmaxf(m, __shfl_xor(m, off));
    __shared__ float redm[4], reds[4];
    const int wid = threadIdx.x >> 6, lane = threadIdx.x & 63;
    if (lane == 0) redm[wid] = m;
    __syncthreads();
    m = fmaxf(fmaxf(redm[0], redm[1]), fmaxf(redm[2], redm[3]));
    float mm = (m == -INFINITY) ? 0.f : m;   // guard NaN (all-masked row can't occur, but cheap)
    float s = 0.f;
    #pragma unroll
    for (int k = 0; k < 8; ++k) s += __expf(v[k] - mm);
    #pragma unroll
    for (int off = 32; off; off >>= 1) s += __shfl_xor(s, off);
    if (lane == 0) reds[wid] = s;
    __syncthreads();
    if (threadIdx.x == 0) {
        rowstats[(size_t)row * 2]     = m;
        rowstats[(size_t)row * 2 + 1] = reds[0] + reds[1] + reds[2] + reds[3];
    }
}

// ---------------------------------------------------------------------------
// Column softmax partials over s (axis=1), masked by src_mask.
// Block = 64 t-lanes x 4 s-sublanes; covers s-chunk of 512. Coalesced 256B rows.
// ---------------------------------------------------------------------------
__global__ __launch_bounds__(256) void colstats_partial_kernel(
    const float* __restrict__ sim, const int* __restrict__ smask,
    float* __restrict__ colpart)
{
    const int b = blockIdx.z, sc = blockIdx.y, t0 = blockIdx.x * 64;
    const int tl = threadIdx.x & 63, ss = threadIdx.x >> 6;
    const float* base = sim + (size_t)b * S_ * T_;
    float m = -INFINITY, sum = 0.f;
    for (int i = 0; i < 128; ++i) {
        int s = sc * 512 + i * 4 + ss;                 // wave-uniform
        if (smask[b * S_ + s]) {
            float x = base[(size_t)s * T_ + t0 + tl];
            if (x > m) { sum = sum * __expf(m - x) + 1.f; m = x; }
            else       { sum += __expf(x - m); }
        }
    }
    __shared__ float pm[4][64], ps[4][64];
    pm[ss][tl] = m; ps[ss][tl] = sum;
    __syncthreads();
    if (ss == 0) {
        float M = fmaxf(fmaxf(pm[0][tl], pm[1][tl]), fmaxf(pm[2][tl], pm[3][tl]));
        float Ss = 0.f;
        if (M != -INFINITY) {
            #pragma unroll
            for (int j = 0; j < 4; ++j) Ss += ps[j][tl] * __expf(pm[j][tl] - M);
        }
        size_t o = (((size_t)b * 4 + sc) * T_ + t0 + tl) * 2;
        colpart[o] = M; colpart[o + 1] = Ss;
    }
}

__global__ void colcombine_kernel(const float* __restrict__ colpart,
                                  float* __restrict__ colstats)
{
    int i = blockIdx.x * 256 + threadIdx.x;   // b*T + t
    if (i >= B_ * T_) return;
    int b = i >> 11, t = i & (T_ - 1);
    float pm[4], ps[4];
    float M = -INFINITY;
    #pragma unroll
    for (int c = 0; c < 4; ++c) {
        size_t o = (((size_t)b * 4 + c) * T_ + t) * 2;
        pm[c] = colpart[o]; ps[c] = colpart[o + 1];
        M = fmaxf(M, pm[c]);
    }
    float Ss = 0.f;
    if (M != -INFINITY) {
        #pragma unroll
        for (int c = 0; c < 4; ++c) Ss += ps[c] * __expf(pm[c] - M);
    }
    colstats[(size_t)i * 2] = M;
    colstats[(size_t)i * 2 + 1] = Ss;
}

// ---------------------------------------------------------------------------
// conf = P1 * P2, plus row-max (over t) and col-max (over s) of conf.
// Same tiling as colstats. conf >= 0 so float-bit atomicMax on uint is exact.
// ---------------------------------------------------------------------------
__global__ __launch_bounds__(256) void conf_kernel(
    const float* __restrict__ sim,
    const float* __restrict__ rowstats, const float* __restrict__ colstats,
    const int* __restrict__ smask, const int* __restrict__ tmask,
    float* __restrict__ conf, unsigned* __restrict__ rowconfmax,
    unsigned* __restrict__ colconfmax)
{
    const int b = blockIdx.z, sc = blockIdx.y, t0 = blockIdx.x * 64;
    const int tl = threadIdx.x & 63, ss = threadIdx.x >> 6;
    const int tg = t0 + tl;
    float2 cstat = *(const float2*)&colstats[((size_t)b * T_ + tg) * 2];
    const float cm = cstat.x, invcs = 1.f / cstat.y;
    const int tmv = tmask[b * T_ + tg];
    const float* base  = sim  + (size_t)b * S_ * T_;
    float*       cbase = conf + (size_t)b * S_ * T_;
    float colmax_local = 0.f;
    for (int i = 0; i < 128; ++i) {
        int s = sc * 512 + i * 4 + ss;                 // wave-uniform
        float2 rstat = *(const float2*)&rowstats[((size_t)b * S_ + s) * 2];
        int smv = smask[b * S_ + s];
        float cv = 0.f;
        if (smv && tmv) {
            float x = base[(size_t)s * T_ + tg];
            cv = __expf(x - cm) * invcs * __expf(x - rstat.x) * (1.f / rstat.y);
        }
        cbase[(size_t)s * T_ + tg] = cv;
        colmax_local = fmaxf(colmax_local, cv);
        float r = cv;
        #pragma unroll
        for (int off = 32; off; off >>= 1) r = fmaxf(r, __shfl_xor(r, off));
        if (tl == 0) atomicMax(&rowconfmax[b * S_ + s], __float_as_uint(r));
    }
    __shared__ float cred[4][64];
    cred[ss][tl] = colmax_local;
    __syncthreads();
    if (ss == 0) {
        float M = fmaxf(fmaxf(cred[0][tl], cred[1][tl]),
                        fmaxf(cred[2][tl], cred[3][tl]));
        atomicMax(&colconfmax[b * T_ + tg], __float_as_uint(M));
    }
}

// ---------------------------------------------------------------------------
// mask = conf > 0.2 && conf == rowmax && conf == colmax  (as 0.0/1.0 floats)
// ---------------------------------------------------------------------------
__global__ __launch_bounds__(256) void maskout_kernel(
    const float* __restrict__ conf,
    const unsigned* __restrict__ rowconfmax, const unsigned* __restrict__ colconfmax,
    float* __restrict__ outmask)
{
    const size_t n4 = (size_t)B_ * S_ * T_ / 4;
    for (size_t i4 = (size_t)blockIdx.x * blockDim.x + threadIdx.x; i4 < n4;
         i4 += (size_t)gridDim.x * blockDim.x) {
        size_t base = i4 * 4;
        int t0  = (int)(base & (T_ - 1));
        int row = (int)(base >> 11);        // b*S + s
        int b   = row >> 11;
        float4 c = *(const float4*)(conf + base);
        float rm = __uint_as_float(rowconfmax[row]);
        const unsigned* cmp = colconfmax + b * T_ + t0;
        float cc[4] = {c.x, c.y, c.z, c.w};
        float o[4];
        #pragma unroll
        for (int j = 0; j < 4; ++j) {
            float cmv = __uint_as_float(cmp[j]);
            o[j] = (cc[j] > 0.2f && cc[j] == rm && cc[j] == cmv) ? 1.f : 0.f;
        }
        *(float4*)(outmask + base) = make_float4(o[0], o[1], o[2], o[3]);
    }
}

extern "C" void kernel_launch(void* const* d_in, const int* in_sizes, int n_in,
                              void* d_out, int out_size, void* d_ws, size_t ws_size,
                              hipStream_t stream)
{
    const float* src_feats = (const float*)d_in[0];
    const float* tgt_feats = (const float*)d_in[1];
    const void*  src_mask  = d_in[2];
    const void*  tgt_mask  = d_in[3];
    const float* W         = (const float*)d_in[4];

    float* conf   = (float*)d_out;                       // [B,S,T] final conf
    float* simbuf = conf + (size_t)B_ * S_ * T_;         // mask region, reused for sim
    float* srcp   = conf;                                // projections staged in conf region
    float* tgtp   = conf + (size_t)B_ * S_ * C_;

    // workspace layout (~512 KB)
    float* ws = (float*)d_ws;
    float*    rowstats   = ws;                               // 2*B*S
    float*    colstats   = rowstats + 2 * B_ * S_;           // 2*B*T
    float*    colpart    = colstats + 2 * B_ * T_;           // 2*4*B*T
    unsigned* rowconfmax = (unsigned*)(colpart + 2 * 4 * B_ * T_);  // B*S
    unsigned* colconfmax = rowconfmax + B_ * S_;             // B*T
    int*      smask      = (int*)(colconfmax + B_ * T_);     // B*S
    int*      tmask      = smask + B_ * S_;                  // B*T

    build_masks_kernel<<<(B_ * S_ + 255) / 256, 256, 0, stream>>>(
        src_mask, tgt_mask, smask, tmask);
    hipMemsetAsync(rowconfmax, 0, (size_t)(B_ * S_ + B_ * T_) * sizeof(unsigned), stream);

    // projections: proj = (feats @ W^T) / 16   (fold /scale; exact pow2)
    gemm_nt_kernel<<<dim3(C_ / 64, B_ * S_ / 64, 1), 256, 0, stream>>>(
        src_feats, W, srcp, B_ * S_, C_, C_, 0, 0, 0, 0.0625f);
    gemm_nt_kernel<<<dim3(C_ / 64, B_ * T_ / 64, 1), 256, 0, stream>>>(
        tgt_feats, W, tgtp, B_ * T_, C_, C_, 0, 0, 0, 0.0625f);

    // sim[b] = 10 * srcp[b] @ tgtp[b]^T
    gemm_nt_kernel<<<dim3(T_ / 64, S_ / 64, B_), 256, 0, stream>>>(
        srcp, tgtp, simbuf, S_, T_, C_,
        (long)S_ * C_, (long)T_ * C_, (long)S_ * T_, 10.0f);

    rowstats_kernel<<<B_ * S_, 256, 0, stream>>>(simbuf, tmask, rowstats);
    colstats_partial_kernel<<<dim3(T_ / 64, 4, B_), 256, 0, stream>>>(
        simbuf, smask, colpart);
    colcombine_kernel<<<(B_ * T_ + 255) / 256, 256, 0, stream>>>(colpart, colstats);

    conf_kernel<<<dim3(T_ / 64, 4, B_), 256, 0, stream>>>(
        simbuf, rowstats, colstats, smask, tmask, conf, rowconfmax, colconfmax);

    maskout_kernel<<<2048, 256, 0, stream>>>(conf, rowconfmax, colconfmax, simbuf);
}

// Round 2
// 368.092 us; speedup vs baseline: 1.5629x; 1.5629x over previous
//
#include <hip/hip_runtime.h>
#include <hip/hip_bf16.h>
#include <cstdint>
#include <cstddef>

#define B_ 4
#define S_ 2048
#define T_ 2048
#define C_ 256

// ---------------------------------------------------------------------------
// Canonicalize masks (bool-byte / int32 / float32 storage all handled).
// Element index 1 is True in this problem (all lens >= 1024), so:
//   byte layout  -> byte[1] == 1;  4-byte layout -> byte[1] == 0
// ---------------------------------------------------------------------------
__global__ void build_masks_kernel(const void* __restrict__ src_mask,
                                   const void* __restrict__ tgt_mask,
                                   int* __restrict__ smask, int* __restrict__ tmask) {
    int i = blockIdx.x * blockDim.x + threadIdx.x;
    const unsigned char* sb = (const unsigned char*)src_mask;
    const unsigned char* tb = (const unsigned char*)tgt_mask;
    bool s_is_byte = (sb[1] != 0);
    bool t_is_byte = (tb[1] != 0);
    if (i < B_ * S_)
        smask[i] = s_is_byte ? (sb[i] != 0) : (((const int*)src_mask)[i] != 0);
    if (i < B_ * T_)
        tmask[i] = t_is_byte ? (tb[i] != 0) : (((const int*)tgt_mask)[i] != 0);
}

// ---------------------------------------------------------------------------
// Projection GEMM (f32 NT): Out[m,n] = scale * sum_k A[m,k]*B[n,k]
// ---------------------------------------------------------------------------
__global__ __launch_bounds__(256) void gemm_nt_kernel(
    const float* __restrict__ A, const float* __restrict__ Bm, float* __restrict__ Out,
    int M, int N, int K, float scale)
{
    __shared__ float As[64][68];
    __shared__ float Bs[64][68];
    const int tid = threadIdx.x;
    const int n0 = blockIdx.x * 64, m0 = blockIdx.y * 64;
    const int c4 = tid & 15;
    const int rl = tid >> 4;
    const int tx = tid & 15, ty = tid >> 4;
    float acc[4][4] = {};

    for (int k0 = 0; k0 < K; k0 += 64) {
        #pragma unroll
        for (int p = 0; p < 4; ++p) {
            int row = p * 16 + rl;
            float4 a = *(const float4*)(A  + (size_t)(m0 + row) * K + k0 + c4 * 4);
            As[c4*4+0][row] = a.x; As[c4*4+1][row] = a.y;
            As[c4*4+2][row] = a.z; As[c4*4+3][row] = a.w;
            float4 b = *(const float4*)(Bm + (size_t)(n0 + row) * K + k0 + c4 * 4);
            Bs[c4*4+0][row] = b.x; Bs[c4*4+1][row] = b.y;
            Bs[c4*4+2][row] = b.z; Bs[c4*4+3][row] = b.w;
        }
        __syncthreads();
        #pragma unroll 8
        for (int k = 0; k < 64; ++k) {
            float4 av = *(const float4*)&As[k][ty * 4];
            float4 bv = *(const float4*)&Bs[k][tx * 4];
            float aa[4] = {av.x, av.y, av.z, av.w};
            float bb[4] = {bv.x, bv.y, bv.z, bv.w};
            #pragma unroll
            for (int i = 0; i < 4; ++i)
                #pragma unroll
                for (int j = 0; j < 4; ++j)
                    acc[i][j] = fmaf(aa[i], bb[j], acc[i][j]);
        }
        __syncthreads();
    }
    #pragma unroll
    for (int i = 0; i < 4; ++i) {
        float4 o = make_float4(acc[i][0]*scale, acc[i][1]*scale,
                               acc[i][2]*scale, acc[i][3]*scale);
        *(float4*)(Out + (size_t)(m0 + ty*4 + i) * N + n0 + tx * 4) = o;
    }
}

// ---------------------------------------------------------------------------
// sim GEMM with fused masked softmax-stat partials.
// sim[b] = 10 * A[b] @ B[b]^T (A=[S,C] srcp, B=[T,C] tgtp), 64x64 tiles.
// Emits per-tile row partials (max,sumexp over 64 t, tmask'd) -> rowpart
//       and col partials (over 64 s, smask'd)                 -> colpart
// ---------------------------------------------------------------------------
__global__ __launch_bounds__(256) void gemm_sim_kernel(
    const float* __restrict__ A, const float* __restrict__ Bm, float* __restrict__ Out,
    const int* __restrict__ smask, const int* __restrict__ tmask,
    float2* __restrict__ rowpart, float2* __restrict__ colpart)
{
    __shared__ float smem[2 * 64 * 68];
    float (*As)[68] = (float(*)[68])smem;
    float (*Bs)[68] = (float(*)[68])(smem + 64 * 68);
    const int b = blockIdx.z;
    const float* Ab = A  + (size_t)b * S_ * C_;
    const float* Bb = Bm + (size_t)b * T_ * C_;
    float* Ob = Out + (size_t)b * S_ * T_;
    const int n0 = blockIdx.x * 64, m0 = blockIdx.y * 64;
    const int tid = threadIdx.x;
    const int c4 = tid & 15, rl = tid >> 4;
    const int tx = tid & 15, ty = tid >> 4;
    float acc[4][4] = {};

    for (int k0 = 0; k0 < C_; k0 += 64) {
        #pragma unroll
        for (int p = 0; p < 4; ++p) {
            int row = p * 16 + rl;
            float4 a = *(const float4*)(Ab + (size_t)(m0 + row) * C_ + k0 + c4 * 4);
            As[c4*4+0][row] = a.x; As[c4*4+1][row] = a.y;
            As[c4*4+2][row] = a.z; As[c4*4+3][row] = a.w;
            float4 bb4 = *(const float4*)(Bb + (size_t)(n0 + row) * C_ + k0 + c4 * 4);
            Bs[c4*4+0][row] = bb4.x; Bs[c4*4+1][row] = bb4.y;
            Bs[c4*4+2][row] = bb4.z; Bs[c4*4+3][row] = bb4.w;
        }
        __syncthreads();
        #pragma unroll 8
        for (int k = 0; k < 64; ++k) {
            float4 av = *(const float4*)&As[k][ty * 4];
            float4 bv = *(const float4*)&Bs[k][tx * 4];
            float aa[4] = {av.x, av.y, av.z, av.w};
            float bbv[4] = {bv.x, bv.y, bv.z, bv.w};
            #pragma unroll
            for (int i = 0; i < 4; ++i)
                #pragma unroll
                for (int j = 0; j < 4; ++j)
                    acc[i][j] = fmaf(aa[i], bbv[j], acc[i][j]);
        }
        __syncthreads();
    }

    // scale by 1/TEMPERATURE and write sim
    #pragma unroll
    for (int i = 0; i < 4; ++i) {
        #pragma unroll
        for (int j = 0; j < 4; ++j) acc[i][j] *= 10.0f;
        *(float4*)(Ob + (size_t)(m0 + ty*4 + i) * T_ + n0 + tx * 4) =
            make_float4(acc[i][0], acc[i][1], acc[i][2], acc[i][3]);
    }

    // masks for this tile
    int4 tm4 = *(const int4*)(tmask + b * T_ + n0 + tx * 4);
    int4 sm4 = *(const int4*)(smask + b * S_ + m0 + ty * 4);
    int tm[4] = {tm4.x, tm4.y, tm4.z, tm4.w};
    int sm[4] = {sm4.x, sm4.y, sm4.z, sm4.w};

    float2 (*red)[17] = (float2(*)[17])smem;   // 64 x 17 float2, aliases As

    // ---- row partials (over t, tmask) ----
    __syncthreads();
    #pragma unroll
    for (int i = 0; i < 4; ++i) {
        float v0 = tm[0] ? acc[i][0] : -INFINITY;
        float v1 = tm[1] ? acc[i][1] : -INFINITY;
        float v2 = tm[2] ? acc[i][2] : -INFINITY;
        float v3 = tm[3] ? acc[i][3] : -INFINITY;
        float m = fmaxf(fmaxf(v0, v1), fmaxf(v2, v3));
        float ss = 0.f;
        if (m != -INFINITY)
            ss = __expf(v0 - m) + __expf(v1 - m) + __expf(v2 - m) + __expf(v3 - m);
        red[ty * 4 + i][tx] = make_float2(m, ss);
    }
    __syncthreads();
    if (tid < 64) {
        float M = -INFINITY;
        #pragma unroll
        for (int q = 0; q < 16; ++q) M = fmaxf(M, red[tid][q].x);
        float SS = 0.f;
        if (M != -INFINITY) {
            #pragma unroll
            for (int q = 0; q < 16; ++q) {
                float2 p = red[tid][q];
                SS += p.y * __expf(p.x - M);
            }
        }
        rowpart[((size_t)(b * S_ + m0 + tid)) * (T_ / 64) + n0 / 64] =
            make_float2(M, SS);
    }
    __syncthreads();

    // ---- col partials (over s, smask) ----
    #pragma unroll
    for (int j = 0; j < 4; ++j) {
        float v0 = sm[0] ? acc[0][j] : -INFINITY;
        float v1 = sm[1] ? acc[1][j] : -INFINITY;
        float v2 = sm[2] ? acc[2][j] : -INFINITY;
        float v3 = sm[3] ? acc[3][j] : -INFINITY;
        float m = fmaxf(fmaxf(v0, v1), fmaxf(v2, v3));
        float ss = 0.f;
        if (m != -INFINITY)
            ss = __expf(v0 - m) + __expf(v1 - m) + __expf(v2 - m) + __expf(v3 - m);
        red[tx * 4 + j][ty] = make_float2(m, ss);
    }
    __syncthreads();
    if (tid < 64) {
        float M = -INFINITY;
        #pragma unroll
        for (int q = 0; q < 16; ++q) M = fmaxf(M, red[tid][q].x);
        float SS = 0.f;
        if (M != -INFINITY) {
            #pragma unroll
            for (int q = 0; q < 16; ++q) {
                float2 p = red[tid][q];
                SS += p.y * __expf(p.x - M);
            }
        }
        colpart[((size_t)(b * T_ + n0 + tid)) * (S_ / 64) + m0 / 64] =
            make_float2(M, SS);
    }
}

// ---------------------------------------------------------------------------
// Merge 32 (max,sumexp) partials per row -> final (max, sumexp)
// ---------------------------------------------------------------------------
__global__ __launch_bounds__(256) void combine_kernel(
    const float2* __restrict__ part, float2* __restrict__ stats, int nrow)
{
    int r = blockIdx.x * 256 + threadIdx.x;
    if (r >= nrow) return;
    const float2* p = part + (size_t)r * 32;
    float2 v[32];
    #pragma unroll
    for (int q = 0; q < 16; ++q) {
        float4 f = *(const float4*)(p + q * 2);
        v[2*q]   = make_float2(f.x, f.y);
        v[2*q+1] = make_float2(f.z, f.w);
    }
    float M = -INFINITY;
    #pragma unroll
    for (int q = 0; q < 32; ++q) M = fmaxf(M, v[q].x);
    float SS = 0.f;
    if (M != -INFINITY) {
        #pragma unroll
        for (int q = 0; q < 32; ++q) SS += v[q].y * __expf(v[q].x - M);
    }
    stats[r] = make_float2(M, SS);
}

// ---------------------------------------------------------------------------
// conf = exp(2x - cm - rm) / (cs*rs) under masks; row/col conf maxima.
// Block: 256 thr = 4 waves; lane owns 4 t (float4); block tile 32 s x 256 t.
// ---------------------------------------------------------------------------
__global__ __launch_bounds__(256) void conf_kernel(
    const float* __restrict__ sim, const float2* __restrict__ rowstats,
    const float2* __restrict__ colstats, const int* __restrict__ smask,
    const int* __restrict__ tmask, float* __restrict__ conf,
    unsigned* __restrict__ rowconfmax, unsigned* __restrict__ colconfmax)
{
    const int b = blockIdx.z;
    const int s0 = blockIdx.y * 32;
    const int t0 = blockIdx.x * 256;
    const int l = threadIdx.x & 63, w = threadIdx.x >> 6;
    const int t = t0 + l * 4;

    const float2* cst = colstats + b * T_ + t;
    float2 c0 = cst[0], c1 = cst[1], c2 = cst[2], c3 = cst[3];
    int4 tm4 = *(const int4*)(tmask + b * T_ + t);
    const int tm[4] = {tm4.x, tm4.y, tm4.z, tm4.w};
    const float cm[4]   = {c0.x, c1.x, c2.x, c3.x};
    const float invc[4] = {1.f / c0.y, 1.f / c1.y, 1.f / c2.y, 1.f / c3.y};

    const float* simb  = sim  + (size_t)b * S_ * T_;
    float*       confb = conf + (size_t)b * S_ * T_;
    float colmax[4] = {0.f, 0.f, 0.f, 0.f};

    #pragma unroll
    for (int it = 0; it < 8; ++it) {
        const int s = s0 + it * 4 + w;
        float2 rst = rowstats[b * S_ + s];
        int smv = smask[b * S_ + s];
        float4 x4 = *(const float4*)(simb + (size_t)s * T_ + t);
        float x[4] = {x4.x, x4.y, x4.z, x4.w};
        float cv[4];
        if (smv) {
            float rm = rst.x, invr = 1.f / rst.y;
            #pragma unroll
            for (int j = 0; j < 4; ++j)
                cv[j] = tm[j]
                    ? __expf(2.f * x[j] - cm[j] - rm) * (invc[j] * invr)
                    : 0.f;
        } else {
            cv[0] = cv[1] = cv[2] = cv[3] = 0.f;
        }
        *(float4*)(confb + (size_t)s * T_ + t) =
            make_float4(cv[0], cv[1], cv[2], cv[3]);

        float rmax = fmaxf(fmaxf(cv[0], cv[1]), fmaxf(cv[2], cv[3]));
        #pragma unroll
        for (int off = 32; off; off >>= 1) rmax = fmaxf(rmax, __shfl_xor(rmax, off));
        if (l == 0 && smv)
            atomicMax(&rowconfmax[b * S_ + s], __float_as_uint(rmax));

        #pragma unroll
        for (int j = 0; j < 4; ++j) colmax[j] = fmaxf(colmax[j], cv[j]);
    }

    __shared__ float cred[4][256];
    *(float4*)&cred[w][l * 4] = make_float4(colmax[0], colmax[1], colmax[2], colmax[3]);
    __syncthreads();
    {
        int tt = threadIdx.x;
        float M = fmaxf(fmaxf(cred[0][tt], cred[1][tt]),
                        fmaxf(cred[2][tt], cred[3][tt]));
        atomicMax(&colconfmax[b * T_ + t0 + tt], __float_as_uint(M));
    }
}

// ---------------------------------------------------------------------------
// mask = conf > 0.2 && conf == rowmax && conf == colmax  (0.0/1.0 floats)
// ---------------------------------------------------------------------------
__global__ __launch_bounds__(256) void maskout_kernel(
    const float* __restrict__ conf,
    const unsigned* __restrict__ rowconfmax, const unsigned* __restrict__ colconfmax,
    float* __restrict__ outmask)
{
    const size_t n4 = (size_t)B_ * S_ * T_ / 4;
    for (size_t i4 = (size_t)blockIdx.x * blockDim.x + threadIdx.x; i4 < n4;
         i4 += (size_t)gridDim.x * blockDim.x) {
        size_t base = i4 * 4;
        int t0  = (int)(base & (T_ - 1));
        int row = (int)(base >> 11);        // b*S + s
        int b   = row >> 11;
        float4 c = *(const float4*)(conf + base);
        float rm = __uint_as_float(rowconfmax[row]);
        const unsigned* cmp = colconfmax + b * T_ + t0;
        float cc[4] = {c.x, c.y, c.z, c.w};
        float o[4];
        #pragma unroll
        for (int j = 0; j < 4; ++j) {
            float cmv = __uint_as_float(cmp[j]);
            o[j] = (cc[j] > 0.2f && cc[j] == rm && cc[j] == cmv) ? 1.f : 0.f;
        }
        *(float4*)(outmask + base) = make_float4(o[0], o[1], o[2], o[3]);
    }
}

extern "C" void kernel_launch(void* const* d_in, const int* in_sizes, int n_in,
                              void* d_out, int out_size, void* d_ws, size_t ws_size,
                              hipStream_t stream)
{
    const float* src_feats = (const float*)d_in[0];
    const float* tgt_feats = (const float*)d_in[1];
    const void*  src_mask  = d_in[2];
    const void*  tgt_mask  = d_in[3];
    const float* W         = (const float*)d_in[4];

    float* conf   = (float*)d_out;                       // [B,S,T] final conf
    float* simbuf = conf + (size_t)B_ * S_ * T_;         // mask region holds sim

    // big scratch staged inside the (not-yet-written) conf region:
    float*  srcp    = conf;                                  // 2M floats
    float*  tgtp    = conf + (size_t)B_ * S_ * C_;           // 2M floats
    float2* rowpart = (float2*)(conf + (size_t)4 * 1024 * 1024);      // B*S*32 f2
    float2* colpart = rowpart + (size_t)B_ * S_ * (T_ / 64);          // B*T*32 f2

    // small scratch in d_ws (~260 KB)
    float2*   rowstats   = (float2*)d_ws;                    // B*S
    float2*   colstats   = rowstats + B_ * S_;               // B*T
    unsigned* rowconfmax = (unsigned*)(colstats + B_ * T_);  // B*S
    unsigned* colconfmax = rowconfmax + B_ * S_;             // B*T
    int*      smask      = (int*)(colconfmax + B_ * T_);     // B*S
    int*      tmask      = smask + B_ * S_;                  // B*T

    hipMemsetAsync(rowconfmax, 0, (size_t)(B_ * S_ + B_ * T_) * sizeof(unsigned),
                   stream);
    build_masks_kernel<<<(B_ * S_ + 255) / 256, 256, 0, stream>>>(
        src_mask, tgt_mask, smask, tmask);

    // projections: proj = (feats @ W^T) / 16   (fold /sqrt(C); exact pow2)
    gemm_nt_kernel<<<dim3(C_ / 64, B_ * S_ / 64), 256, 0, stream>>>(
        src_feats, W, srcp, B_ * S_, C_, C_, 0.0625f);
    gemm_nt_kernel<<<dim3(C_ / 64, B_ * T_ / 64), 256, 0, stream>>>(
        tgt_feats, W, tgtp, B_ * T_, C_, C_, 0.0625f);

    // sim = 10 * srcp @ tgtp^T  (+ fused masked softmax stat partials)
    gemm_sim_kernel<<<dim3(T_ / 64, S_ / 64, B_), 256, 0, stream>>>(
        srcp, tgtp, simbuf, smask, tmask, rowpart, colpart);

    combine_kernel<<<(B_ * S_ + 255) / 256, 256, 0, stream>>>(
        rowpart, rowstats, B_ * S_);
    combine_kernel<<<(B_ * T_ + 255) / 256, 256, 0, stream>>>(
        colpart, colstats, B_ * T_);

    conf_kernel<<<dim3(T_ / 256, S_ / 32, B_), 256, 0, stream>>>(
        simbuf, rowstats, colstats, smask, tmask, conf, rowconfmax, colconfmax);

    maskout_kernel<<<4096, 256, 0, stream>>>(conf, rowconfmax, colconfmax, simbuf);
}